// Round 19
// baseline (86.793 us; speedup 1.0000x reference)
//
#include <hip/hip_runtime.h>
#include <hip/hip_bf16.h>
#include <stdint.h>

#define B_   2
#define S_   2048
#define HID_ 1024
#define NH_  16
#define HD_  64

typedef __attribute__((ext_vector_type(4))) float f32x4;
typedef __attribute__((ext_vector_type(8))) short bf16x8;

__device__ inline unsigned short f2bf(float x) {
    __hip_bfloat16 h = __float2bfloat16(x);
    return reinterpret_cast<unsigned short&>(h);
}

__device__ inline void gload_lds16(const void* g, void* l) {
    __builtin_amdgcn_global_load_lds(
        (const __attribute__((address_space(1))) void*)g,
        (__attribute__((address_space(3))) void*)l, 16, 0, 0);
}

__device__ inline float fast_exp2(float x) {
    float r;
    asm("v_exp_f32 %0, %1" : "=v"(r) : "v"(x));
    return r;
}

// ---------------------------------------------------------------------------
// Pass 0: fp32 -> bf16 conversion of X1, X2, Wq, Wk, Wv (unchanged).
// ---------------------------------------------------------------------------
__global__ __launch_bounds__(256) void cvt_all(
    const float* __restrict__ X1, const float* __restrict__ X2,
    const float* __restrict__ Wq, const float* __restrict__ Wk, const float* __restrict__ Wv,
    unsigned short* __restrict__ X1b, unsigned short* __restrict__ X2b,
    unsigned short* __restrict__ Wqb, unsigned short* __restrict__ Wkb,
    unsigned short* __restrict__ Wvb)
{
    const int id = blockIdx.x;
    const float* src;
    unsigned short* dst;
    int base;
    if (id < 2048)      { src = X1; dst = X1b; base = id; }
    else if (id < 4096) { src = X2; dst = X2b; base = id - 2048; }
    else if (id < 4608) { src = Wq; dst = Wqb; base = id - 4096; }
    else if (id < 5120) { src = Wk; dst = Wkb; base = id - 4608; }
    else                { src = Wv; dst = Wvb; base = id - 5120; }
    const size_t off = (size_t)base * 2048 + (size_t)threadIdx.x * 8;
    float4 a = *(const float4*)&src[off];
    float4 b = *(const float4*)&src[off + 4];
    unsigned short o[8] = {f2bf(a.x), f2bf(a.y), f2bf(a.z), f2bf(a.w),
                           f2bf(b.x), f2bf(b.y), f2bf(b.z), f2bf(b.w)};
    *(uint4*)&dst[off] = *(uint4*)o;
}

// ---------------------------------------------------------------------------
// QKV projection: 128x128 tile, BK=32, DOUBLE-BUFFERED (32 KB staging, keeps
// 3 blocks/CU) with counted-vmcnt pipelining (the R15/R17 attn pattern):
// barrier(a) -> STAGE(next) -> s_waitcnt vmcnt(4) -> barrier(b) -> compute.
// The stage flies across a full k-step instead of draining at the barrier
// (removes the m97 ~20% drain stall). T21 swizzle re-derived for 64B rows:
// stage src slot (lane&3)^(((lane>>2)>>1)&3); read slot hi^((lo>>1)&3);
// 2-way banks (free). z==0 Q (scaled), z==1 K, z==2 V (transposed out).
// ---------------------------------------------------------------------------
__global__ __launch_bounds__(256, 3) void qkv_gemm(
    const unsigned short* __restrict__ X1b, const unsigned short* __restrict__ X2b,
    const unsigned short* __restrict__ Wqb, const unsigned short* __restrict__ Wkb,
    const unsigned short* __restrict__ Wvb,
    const float* __restrict__ bq, const float* __restrict__ bk, const float* __restrict__ bv,
    unsigned short* __restrict__ Qo, unsigned short* __restrict__ Ko, unsigned short* __restrict__ Vo)
{
    const int z = blockIdx.z;
    const unsigned short* X = (z == 0) ? X1b : X2b;
    const unsigned short* W = (z == 0) ? Wqb : (z == 1 ? Wkb : Wvb);
    const float* bias = (z == 0) ? bq : (z == 1 ? bk : bv);
    unsigned short* out = (z == 0) ? Qo : (z == 1 ? Ko : Vo);

    // staging: buf b at SM + b*8192: A[128][32] | B[128][32] (8 KB each).
    // V-transpose epilogue Ts[128][132] (33.8 KB) aliases everything.
    __shared__ __align__(16) unsigned short SM[16896];

    const int m0 = blockIdx.x * 128;
    const int n0 = blockIdx.y * 128;
    const int t = threadIdx.x;
    const int lane = t & 63;
    const int w = t >> 6;
    const int lo = lane & 15, hi = lane >> 4;
    const int wm = w >> 1, wn = w & 1;

    // staging decomposition: r16 = lane>>2 (row in 16-row sweep), c4 = lane&3
    const int r16 = lane >> 2;
    const int scol = ((lane & 3) ^ ((r16 >> 1) & 3)) * 8;   // swizzled src col

    f32x4 acc[4][4];
    const f32x4 fzero = {0.f, 0.f, 0.f, 0.f};
    #pragma unroll
    for (int i = 0; i < 4; ++i)
        #pragma unroll
        for (int j = 0; j < 4; ++j) acc[i][j] = fzero;

    auto STAGE = [&](int buf, int kt) {
        unsigned short* Ab = SM + buf * 8192;
        unsigned short* Bb = Ab + 4096;
        #pragma unroll
        for (int i = 0; i < 2; ++i) {
            const int row = w * 32 + i * 16 + r16;
            gload_lds16(&X[(size_t)(m0 + row) * HID_ + kt * 32 + scol],
                        &Ab[(w * 32 + i * 16) * 32]);
            gload_lds16(&W[(size_t)(n0 + row) * HID_ + kt * 32 + scol],
                        &Bb[(w * 32 + i * 16) * 32]);
        }
    };

    STAGE(0, 0);   // 4 loads in flight for k-step 0

    const int rslot = (hi ^ ((lo >> 1) & 3)) * 8;   // swizzled read col

    for (int kt = 0; kt < 32; ++kt) {
        const int cur = kt & 1;
        const bool pre = (kt < 31);

        // (a) all waves done reading buf[cur^1] -> safe to overwrite
        __builtin_amdgcn_s_barrier();
        if (pre) STAGE(cur ^ 1, kt + 1);   // 4 loads fly during this k-step

        // my current k-step's 4 loads landed; next step's 4 stay in flight
        if (pre) asm volatile("s_waitcnt vmcnt(4)" ::: "memory");
        else     asm volatile("s_waitcnt vmcnt(0)" ::: "memory");
        __builtin_amdgcn_s_barrier();      // (b) everyone's data landed
        __builtin_amdgcn_sched_barrier(0);

        const unsigned short* Ab = SM + cur * 8192;
        const unsigned short* Bb = Ab + 4096;

        bf16x8 a[4], b[4];
        #pragma unroll
        for (int i = 0; i < 4; ++i) {
            a[i] = *(const bf16x8*)&Ab[(wm * 64 + i * 16 + lo) * 32 + rslot];
            b[i] = *(const bf16x8*)&Bb[(wn * 64 + i * 16 + lo) * 32 + rslot];
        }
        __builtin_amdgcn_s_setprio(1);
        #pragma unroll
        for (int i = 0; i < 4; ++i)
            #pragma unroll
            for (int j = 0; j < 4; ++j)
                acc[i][j] = __builtin_amdgcn_mfma_f32_16x16x32_bf16(a[i], b[j], acc[i][j], 0, 0, 0);
        __builtin_amdgcn_s_setprio(0);
    }

    if (z != 2) {
        const float sc = (z == 0) ? 0.18033688011112042f : 1.0f;
        #pragma unroll
        for (int i = 0; i < 4; ++i) {
            #pragma unroll
            for (int j = 0; j < 4; ++j) {
                int col = n0 + wn * 64 + j * 16 + lo;
                float bb = bias[col];
                #pragma unroll
                for (int r = 0; r < 4; ++r) {
                    int row = m0 + wm * 64 + i * 16 + hi * 4 + r;
                    out[(size_t)row * HID_ + col] = f2bf((acc[i][j][r] + bb) * sc);
                }
            }
        }
    } else {
        __syncthreads();
        unsigned short* Ts = SM;   // [128][132]
        #pragma unroll
        for (int i = 0; i < 4; ++i) {
            #pragma unroll
            for (int j = 0; j < 4; ++j) {
                int nl = wn * 64 + j * 16 + lo;
                float bb = bias[n0 + nl];
                int ml = wm * 64 + i * 16 + hi * 4;
                ushort4 pk;
                pk.x = f2bf(acc[i][j][0] + bb);
                pk.y = f2bf(acc[i][j][1] + bb);
                pk.z = f2bf(acc[i][j][2] + bb);
                pk.w = f2bf(acc[i][j][3] + bb);
                *(ushort4*)&Ts[nl * 132 + ml] = pk;
            }
        }
        __syncthreads();
        const int nn = t >> 1;
        const int mh = (t & 1) * 64;
        const int bI = m0 >> 11;
        const int sb = (m0 & 2047) + mh;
        size_t obase = (size_t)bI * ((size_t)HID_ * S_) + (size_t)(n0 + nn) * S_ + sb;
        #pragma unroll
        for (int kk = 0; kk < 8; ++kk)
            *(uint4*)&out[obase + kk * 8] = *(const uint4*)&Ts[nn * 132 + mh + kk * 8];
    }
}

// ---------------------------------------------------------------------------
// Flash attention (unchanged from round 18): 2q x 2k wave split, KVBLK=128,
// counted-vmcnt staging, T21 swizzles, v_exp softmax (static max),
// MFMA denominator, in-register P, LDS epilogue combine.
// ---------------------------------------------------------------------------
__global__ __launch_bounds__(256, 2) void attn_fwd(
    const unsigned short* __restrict__ Q, const unsigned short* __restrict__ K,
    const unsigned short* __restrict__ Vt, float* __restrict__ out)
{
    __shared__ __align__(16) unsigned short SM2[32768];   // 64 KB
    unsigned short* KsBase = SM2;            // Ks[2][128*64]
    unsigned short* VsBase = SM2 + 16384;    // Vs[2][64*128]

    const int t = threadIdx.x;
    const int lane = t & 63;
    const int w = t >> 6;
    const int wq = w & 1, wk = w >> 1;
    const int lo = lane & 15, hi = lane >> 4;

    const int id = blockIdx.x + 16 * blockIdx.y;
    const int vb = (id & 7) * 64 + (id >> 3);
    const int qt = vb & 15;
    const int bh = vb >> 4;
    const int b = bh >> 4, h = bh & 15;

    const int q0 = qt * 128;
    const size_t baseQK = (size_t)b * S_ * HID_ + (size_t)h * HD_;
    const size_t baseV  = (size_t)b * ((size_t)HID_ * S_) + (size_t)h * ((size_t)HD_ * S_);

    bf16x8 qb[4][2];
    #pragma unroll
    for (int qf = 0; qf < 4; ++qf)
        #pragma unroll
        for (int sd = 0; sd < 2; ++sd)
            qb[qf][sd] = *(const bf16x8*)&Q[baseQK + (size_t)(q0 + wq * 64 + qf * 16 + lo) * HID_
                                            + sd * 32 + hi * 8];

    f32x4 O[4][4];
    const f32x4 fzero = {0.f, 0.f, 0.f, 0.f};
    f32x4 lacc[4] = {fzero, fzero, fzero, fzero};
    #pragma unroll
    for (int qf = 0; qf < 4; ++qf)
        #pragma unroll
        for (int c = 0; c < 4; ++c) O[qf][c] = fzero;

    bf16x8 ones;
    #pragma unroll
    for (int j = 0; j < 4; ++j) ((unsigned*)&ones)[j] = 0x3F803F80u;

    const int srow = lane >> 3;
    const int scolK = ((lane & 7) ^ srow) * 8;

    auto STAGE = [&](int buf, int kn) {
        unsigned short* Kb = KsBase + buf * 8192;
        unsigned short* Vb = VsBase + buf * 8192;
        #pragma unroll
        for (int i = 0; i < 4; ++i) {
            const int rr = w * 32 + i * 8 + srow;
            gload_lds16(&K[baseQK + (size_t)(kn + rr) * HID_ + scolK],
                        &Kb[(w * 32 + i * 8) * 64]);
        }
        #pragma unroll
        for (int i = 0; i < 4; ++i) {
            const int rv = w * 16 + i * 4 + (lane >> 4);
            const int sv = ((lane & 15) ^ (rv & 15)) * 8;
            gload_lds16(&Vt[baseV + (size_t)rv * S_ + kn + sv],
                        &Vb[(w * 16 + i * 4) * 128]);
        }
    };

    STAGE(0, 0);

    for (int tt = 0; tt < 16; ++tt) {
        const int cur = tt & 1;
        const bool pre = (tt < 15);

        __builtin_amdgcn_s_barrier();
        if (pre) STAGE(cur ^ 1, (tt + 1) * 128);

        if (pre) asm volatile("s_waitcnt vmcnt(8)" ::: "memory");
        else     asm volatile("s_waitcnt vmcnt(0)" ::: "memory");
        __builtin_amdgcn_s_barrier();
        __builtin_amdgcn_sched_barrier(0);

        const unsigned short* Kc = KsBase + cur * 8192;
        const unsigned short* Vc = VsBase + cur * 8192;

        #pragma unroll
        for (int st = 0; st < 2; ++st) {
            f32x4 s[4][2];
            __builtin_amdgcn_s_setprio(1);
            #pragma unroll
            for (int n2 = 0; n2 < 2; ++n2) {
                const int row = wk * 64 + st * 32 + n2 * 16 + lo;
                const int rc0 = (hi ^ (lo & 7)) * 8;
                const int rc1 = ((4 + hi) ^ (lo & 7)) * 8;
                bf16x8 ka0 = *(const bf16x8*)&Kc[row * 64 + rc0];
                bf16x8 ka1 = *(const bf16x8*)&Kc[row * 64 + rc1];
                #pragma unroll
                for (int qf = 0; qf < 4; ++qf) {
                    f32x4 zc = fzero;
                    zc = __builtin_amdgcn_mfma_f32_16x16x32_bf16(ka0, qb[qf][0], zc, 0, 0, 0);
                    s[qf][n2] = __builtin_amdgcn_mfma_f32_16x16x32_bf16(ka1, qb[qf][1], zc, 0, 0, 0);
                }
            }
            __builtin_amdgcn_s_setprio(0);

            bf16x8 pa[4];
            #pragma unroll
            for (int qf = 0; qf < 4; ++qf) {
                #pragma unroll
                for (int n2 = 0; n2 < 2; ++n2)
                    #pragma unroll
                    for (int r = 0; r < 4; ++r) s[qf][n2][r] = fast_exp2(s[qf][n2][r]);
                unsigned pw[4];
                #pragma unroll
                for (int p = 0; p < 2; ++p) {
                    unsigned X, Y;
                    asm("v_cvt_pk_bf16_f32 %0, %1, %2"
                        : "=v"(X) : "v"(s[qf][0][2 * p]), "v"(s[qf][0][2 * p + 1]));
                    asm("v_cvt_pk_bf16_f32 %0, %1, %2"
                        : "=v"(Y) : "v"(s[qf][1][2 * p]), "v"(s[qf][1][2 * p + 1]));
                    asm volatile("v_permlane32_swap_b32 %0, %1" : "+v"(X), "+v"(Y));
                    asm volatile("v_permlane16_swap_b32 %0, %1" : "+v"(X), "+v"(Y));
                    pw[p] = X;
                    pw[p + 2] = Y;
                }
                #pragma unroll
                for (int j = 0; j < 4; ++j) ((unsigned*)&pa[qf])[j] = pw[j];
            }

            __builtin_amdgcn_s_setprio(1);
            #pragma unroll
            for (int c = 0; c < 4; ++c) {
                const int slot = ((wk * 8 + st * 4 + hi) ^ lo) * 8;
                bf16x8 vbf = *(const bf16x8*)&Vc[(c * 16 + lo) * 128 + slot];
                #pragma unroll
                for (int qf = 0; qf < 4; ++qf)
                    O[qf][c] = __builtin_amdgcn_mfma_f32_16x16x32_bf16(pa[qf], vbf, O[qf][c], 0, 0, 0);
            }
            #pragma unroll
            for (int qf = 0; qf < 4; ++qf)
                lacc[qf] = __builtin_amdgcn_mfma_f32_16x16x32_bf16(pa[qf], ones, lacc[qf], 0, 0, 0);
            __builtin_amdgcn_s_setprio(0);
        }
    }

    __syncthreads();
    float* Obuf = (float*)SM2;                 // [64 d][132] f32
    float* Lbuf = (float*)(SM2 + 16896);       // 128 f32

    if (wk == 1) {
        #pragma unroll
        for (int qf = 0; qf < 4; ++qf) {
            #pragma unroll
            for (int c = 0; c < 4; ++c)
                *(float4*)&Obuf[(c * 16 + lo) * 132 + wq * 64 + qf * 16 + hi * 4] =
                    *(float4*)&O[qf][c];
            #pragma unroll
            for (int r = 0; r < 4; ++r)
                Lbuf[wq * 64 + qf * 16 + hi * 4 + r] = lacc[qf][r];
        }
    }
    __syncthreads();
    if (wk == 0) {
        #pragma unroll
        for (int qf = 0; qf < 4; ++qf) {
            float linv[4];
            #pragma unroll
            for (int r = 0; r < 4; ++r)
                linv[r] = 1.0f / (lacc[qf][r] + Lbuf[wq * 64 + qf * 16 + hi * 4 + r]);
            #pragma unroll
            for (int c = 0; c < 4; ++c) {
                float4 p = *(float4*)&Obuf[(c * 16 + lo) * 132 + wq * 64 + qf * 16 + hi * 4];
                #pragma unroll
                for (int r = 0; r < 4; ++r) {
                    int q = q0 + wq * 64 + qf * 16 + hi * 4 + r;
                    out[(size_t)b * S_ * HID_ + (size_t)q * HID_ + h * HD_ + c * 16 + lo] =
                        (O[qf][c][r] + (&p.x)[r]) * linv[r];
                }
            }
        }
    }
}

extern "C" void kernel_launch(void* const* d_in, const int* in_sizes, int n_in,
                              void* d_out, int out_size, void* d_ws, size_t ws_size,
                              hipStream_t stream) {
    const float* hs1 = (const float*)d_in[0];
    const float* hs2 = (const float*)d_in[1];
    const float* Wq  = (const float*)d_in[2];
    const float* bq  = (const float*)d_in[3];
    const float* Wk  = (const float*)d_in[4];
    const float* bk  = (const float*)d_in[5];
    const float* Wv  = (const float*)d_in[6];
    const float* bv  = (const float*)d_in[7];
    float* out = (float*)d_out;

    const size_t XY = (size_t)B_ * S_ * HID_;   // 4194304
    const size_t WW = (size_t)HID_ * HID_;      // 1048576
    unsigned short* Qb  = (unsigned short*)d_ws;
    unsigned short* Kb  = Qb + XY;
    unsigned short* Vb  = Kb + XY;              // V transposed [b][h*64+d][s]
    unsigned short* X1b = Vb + XY;
    unsigned short* X2b = X1b + XY;
    unsigned short* Wqb = X2b + XY;
    unsigned short* Wkb = Wqb + WW;
    unsigned short* Wvb = Wkb + WW;

    cvt_all<<<5632, 256, 0, stream>>>(hs1, hs2, Wq, Wk, Wv, X1b, X2b, Wqb, Wkb, Wvb);
    qkv_gemm<<<dim3(32, 8, 3), 256, 0, stream>>>(X1b, X2b, Wqb, Wkb, Wvb,
                                                 bq, bk, bv, Qb, Kb, Vb);
    attn_fwd<<<dim3(16, 32), 256, 0, stream>>>(Qb, Kb, Vb, out);
}

// Round 20
// 80.637 us; speedup vs baseline: 1.0763x; 1.0763x over previous
//
#include <hip/hip_runtime.h>
#include <hip/hip_bf16.h>
#include <stdint.h>

#define B_   2
#define S_   2048
#define HID_ 1024
#define NH_  16
#define HD_  64

typedef __attribute__((ext_vector_type(4))) float f32x4;
typedef __attribute__((ext_vector_type(8))) short bf16x8;

__device__ inline unsigned short f2bf(float x) {
    __hip_bfloat16 h = __float2bfloat16(x);
    return reinterpret_cast<unsigned short&>(h);
}

__device__ inline void gload_lds16(const void* g, void* l) {
    __builtin_amdgcn_global_load_lds(
        (const __attribute__((address_space(1))) void*)g,
        (__attribute__((address_space(3))) void*)l, 16, 0, 0);
}

__device__ inline float fast_exp2(float x) {
    float r;
    asm("v_exp_f32 %0, %1" : "=v"(r) : "v"(x));
    return r;
}

// ---------------------------------------------------------------------------
// Pass 0: fp32 -> bf16 conversion of X1, X2, Wq, Wk, Wv (unchanged).
// ---------------------------------------------------------------------------
__global__ __launch_bounds__(256) void cvt_all(
    const float* __restrict__ X1, const float* __restrict__ X2,
    const float* __restrict__ Wq, const float* __restrict__ Wk, const float* __restrict__ Wv,
    unsigned short* __restrict__ X1b, unsigned short* __restrict__ X2b,
    unsigned short* __restrict__ Wqb, unsigned short* __restrict__ Wkb,
    unsigned short* __restrict__ Wvb)
{
    const int id = blockIdx.x;
    const float* src;
    unsigned short* dst;
    int base;
    if (id < 2048)      { src = X1; dst = X1b; base = id; }
    else if (id < 4096) { src = X2; dst = X2b; base = id - 2048; }
    else if (id < 4608) { src = Wq; dst = Wqb; base = id - 4096; }
    else if (id < 5120) { src = Wk; dst = Wkb; base = id - 4608; }
    else                { src = Wv; dst = Wvb; base = id - 5120; }
    const size_t off = (size_t)base * 2048 + (size_t)threadIdx.x * 8;
    float4 a = *(const float4*)&src[off];
    float4 b = *(const float4*)&src[off + 4];
    unsigned short o[8] = {f2bf(a.x), f2bf(a.y), f2bf(a.z), f2bf(a.w),
                           f2bf(b.x), f2bf(b.y), f2bf(b.z), f2bf(b.w)};
    *(uint4*)&dst[off] = *(uint4*)o;
}

// ---------------------------------------------------------------------------
// QKV projection: 128x128 tile, BK=64, SINGLE-buffer pipelined. Once each
// wave's 16 ds_read_b128 fragments are in registers the LDS tile is dead,
// so the next k-step's DMA overwrites it WHILE the 32 MFMAs run on regs:
//   vmcnt(0); barrier -> ds_read frags -> lgkmcnt(0); barrier ->
//   STAGE(kt+1) -> MFMAs.
// The vmcnt(0) wait thus sits AFTER a full MFMA phase (removes the m97
// drain stall) with NO extra LDS (33 KB, 3 blocks/CU) and the same barrier
// count as round 17. T21 involution swizzle unchanged.
// z==0 Q (scaled by 0.125*log2(e)), z==1 K, z==2 V (transposed out).
// ---------------------------------------------------------------------------
__global__ __launch_bounds__(256, 3) void qkv_gemm(
    const unsigned short* __restrict__ X1b, const unsigned short* __restrict__ X2b,
    const unsigned short* __restrict__ Wqb, const unsigned short* __restrict__ Wkb,
    const unsigned short* __restrict__ Wvb,
    const float* __restrict__ bq, const float* __restrict__ bk, const float* __restrict__ bv,
    unsigned short* __restrict__ Qo, unsigned short* __restrict__ Ko, unsigned short* __restrict__ Vo)
{
    const int z = blockIdx.z;
    const unsigned short* X = (z == 0) ? X1b : X2b;
    const unsigned short* W = (z == 0) ? Wqb : (z == 1 ? Wkb : Wvb);
    const float* bias = (z == 0) ? bq : (z == 1 ? bk : bv);
    unsigned short* out = (z == 0) ? Qo : (z == 1 ? Ko : Vo);

    // A[128][64] | B[128][64] staging (32 KB); Ts[128][132] epilogue alias.
    __shared__ __align__(16) unsigned short SM[16896];
    unsigned short* As = SM;
    unsigned short* Bs = SM + 128 * 64;

    const int m0 = blockIdx.x * 128;
    const int n0 = blockIdx.y * 128;
    const int t = threadIdx.x;
    const int lane = t & 63;
    const int w = t >> 6;
    const int lo = lane & 15, hi = lane >> 4;
    const int wm = w >> 1, wn = w & 1;

    const int srow = lane >> 3;
    const int scol = ((lane & 7) ^ srow) * 8;

    f32x4 acc[4][4];
    const f32x4 fzero = {0.f, 0.f, 0.f, 0.f};
    #pragma unroll
    for (int i = 0; i < 4; ++i)
        #pragma unroll
        for (int j = 0; j < 4; ++j) acc[i][j] = fzero;

    auto STAGE = [&](int kt) {
        #pragma unroll
        for (int i = 0; i < 4; ++i) {
            const int r = w * 32 + i * 8 + srow;
            gload_lds16(&X[(size_t)(m0 + r) * HID_ + kt * 64 + scol],
                        &As[w * 2048 + i * 512]);
            gload_lds16(&W[(size_t)(n0 + r) * HID_ + kt * 64 + scol],
                        &Bs[w * 2048 + i * 512]);
        }
    };

    STAGE(0);   // 8 loads in flight for k-step 0

    for (int kt = 0; kt < 16; ++kt) {
        // stage(kt)'s DMA landed (my 8 loads); barrier => everyone's landed
        asm volatile("s_waitcnt vmcnt(0)" ::: "memory");
        __builtin_amdgcn_s_barrier();
        __builtin_amdgcn_sched_barrier(0);

        // pull the whole k-step's fragments into registers (16 x b128)
        bf16x8 a[2][4], b[2][4];
        #pragma unroll
        for (int s = 0; s < 2; ++s) {
            const int rcol = ((s * 4 + hi) ^ (lo & 7)) * 8;
            #pragma unroll
            for (int i = 0; i < 4; ++i) {
                a[s][i] = *(const bf16x8*)&As[(wm * 64 + i * 16 + lo) * 64 + rcol];
                b[s][i] = *(const bf16x8*)&Bs[(wn * 64 + i * 16 + lo) * 64 + rcol];
            }
        }
        __builtin_amdgcn_sched_barrier(0);
        asm volatile("s_waitcnt lgkmcnt(0)" ::: "memory");
        __builtin_amdgcn_s_barrier();      // all waves' frags safe in regs
        __builtin_amdgcn_sched_barrier(0);

        if (kt < 15) STAGE(kt + 1);        // DMA overwrites buf under the MFMAs
        __builtin_amdgcn_sched_barrier(0);

        __builtin_amdgcn_s_setprio(1);
        #pragma unroll
        for (int s = 0; s < 2; ++s)
            #pragma unroll
            for (int i = 0; i < 4; ++i)
                #pragma unroll
                for (int j = 0; j < 4; ++j)
                    acc[i][j] = __builtin_amdgcn_mfma_f32_16x16x32_bf16(a[s][i], b[s][j], acc[i][j], 0, 0, 0);
        __builtin_amdgcn_s_setprio(0);
    }

    if (z != 2) {
        const float sc = (z == 0) ? 0.18033688011112042f : 1.0f;
        #pragma unroll
        for (int i = 0; i < 4; ++i) {
            #pragma unroll
            for (int j = 0; j < 4; ++j) {
                int col = n0 + wn * 64 + j * 16 + lo;
                float bb = bias[col];
                #pragma unroll
                for (int r = 0; r < 4; ++r) {
                    int row = m0 + wm * 64 + i * 16 + hi * 4 + r;
                    out[(size_t)row * HID_ + col] = f2bf((acc[i][j][r] + bb) * sc);
                }
            }
        }
    } else {
        __syncthreads();
        unsigned short* Ts = SM;   // [128][132]
        #pragma unroll
        for (int i = 0; i < 4; ++i) {
            #pragma unroll
            for (int j = 0; j < 4; ++j) {
                int nl = wn * 64 + j * 16 + lo;
                float bb = bias[n0 + nl];
                int ml = wm * 64 + i * 16 + hi * 4;
                ushort4 pk;
                pk.x = f2bf(acc[i][j][0] + bb);
                pk.y = f2bf(acc[i][j][1] + bb);
                pk.z = f2bf(acc[i][j][2] + bb);
                pk.w = f2bf(acc[i][j][3] + bb);
                *(ushort4*)&Ts[nl * 132 + ml] = pk;
            }
        }
        __syncthreads();
        const int nn = t >> 1;
        const int mh = (t & 1) * 64;
        const int bI = m0 >> 11;
        const int sb = (m0 & 2047) + mh;
        size_t obase = (size_t)bI * ((size_t)HID_ * S_) + (size_t)(n0 + nn) * S_ + sb;
        #pragma unroll
        for (int kk = 0; kk < 8; ++kk)
            *(uint4*)&out[obase + kk * 8] = *(const uint4*)&Ts[nn * 132 + mh + kk * 8];
    }
}

// ---------------------------------------------------------------------------
// Flash attention (unchanged from round 18 — best known): 2q x 2k wave
// split, KVBLK=128, counted-vmcnt staging, T21 swizzles, v_exp softmax
// (static max), MFMA denominator, in-register P, LDS epilogue combine.
// ---------------------------------------------------------------------------
__global__ __launch_bounds__(256, 2) void attn_fwd(
    const unsigned short* __restrict__ Q, const unsigned short* __restrict__ K,
    const unsigned short* __restrict__ Vt, float* __restrict__ out)
{
    __shared__ __align__(16) unsigned short SM2[32768];   // 64 KB
    unsigned short* KsBase = SM2;            // Ks[2][128*64]
    unsigned short* VsBase = SM2 + 16384;    // Vs[2][64*128]

    const int t = threadIdx.x;
    const int lane = t & 63;
    const int w = t >> 6;
    const int wq = w & 1, wk = w >> 1;
    const int lo = lane & 15, hi = lane >> 4;

    const int id = blockIdx.x + 16 * blockIdx.y;
    const int vb = (id & 7) * 64 + (id >> 3);
    const int qt = vb & 15;
    const int bh = vb >> 4;
    const int b = bh >> 4, h = bh & 15;

    const int q0 = qt * 128;
    const size_t baseQK = (size_t)b * S_ * HID_ + (size_t)h * HD_;
    const size_t baseV  = (size_t)b * ((size_t)HID_ * S_) + (size_t)h * ((size_t)HD_ * S_);

    bf16x8 qb[4][2];
    #pragma unroll
    for (int qf = 0; qf < 4; ++qf)
        #pragma unroll
        for (int sd = 0; sd < 2; ++sd)
            qb[qf][sd] = *(const bf16x8*)&Q[baseQK + (size_t)(q0 + wq * 64 + qf * 16 + lo) * HID_
                                            + sd * 32 + hi * 8];

    f32x4 O[4][4];
    const f32x4 fzero = {0.f, 0.f, 0.f, 0.f};
    f32x4 lacc[4] = {fzero, fzero, fzero, fzero};
    #pragma unroll
    for (int qf = 0; qf < 4; ++qf)
        #pragma unroll
        for (int c = 0; c < 4; ++c) O[qf][c] = fzero;

    bf16x8 ones;
    #pragma unroll
    for (int j = 0; j < 4; ++j) ((unsigned*)&ones)[j] = 0x3F803F80u;

    const int srow = lane >> 3;
    const int scolK = ((lane & 7) ^ srow) * 8;

    auto STAGE = [&](int buf, int kn) {
        unsigned short* Kb = KsBase + buf * 8192;
        unsigned short* Vb = VsBase + buf * 8192;
        #pragma unroll
        for (int i = 0; i < 4; ++i) {
            const int rr = w * 32 + i * 8 + srow;
            gload_lds16(&K[baseQK + (size_t)(kn + rr) * HID_ + scolK],
                        &Kb[(w * 32 + i * 8) * 64]);
        }
        #pragma unroll
        for (int i = 0; i < 4; ++i) {
            const int rv = w * 16 + i * 4 + (lane >> 4);
            const int sv = ((lane & 15) ^ (rv & 15)) * 8;
            gload_lds16(&Vt[baseV + (size_t)rv * S_ + kn + sv],
                        &Vb[(w * 16 + i * 4) * 128]);
        }
    };

    STAGE(0, 0);

    for (int tt = 0; tt < 16; ++tt) {
        const int cur = tt & 1;
        const bool pre = (tt < 15);

        __builtin_amdgcn_s_barrier();
        if (pre) STAGE(cur ^ 1, (tt + 1) * 128);

        if (pre) asm volatile("s_waitcnt vmcnt(8)" ::: "memory");
        else     asm volatile("s_waitcnt vmcnt(0)" ::: "memory");
        __builtin_amdgcn_s_barrier();
        __builtin_amdgcn_sched_barrier(0);

        const unsigned short* Kc = KsBase + cur * 8192;
        const unsigned short* Vc = VsBase + cur * 8192;

        #pragma unroll
        for (int st = 0; st < 2; ++st) {
            f32x4 s[4][2];
            __builtin_amdgcn_s_setprio(1);
            #pragma unroll
            for (int n2 = 0; n2 < 2; ++n2) {
                const int row = wk * 64 + st * 32 + n2 * 16 + lo;
                const int rc0 = (hi ^ (lo & 7)) * 8;
                const int rc1 = ((4 + hi) ^ (lo & 7)) * 8;
                bf16x8 ka0 = *(const bf16x8*)&Kc[row * 64 + rc0];
                bf16x8 ka1 = *(const bf16x8*)&Kc[row * 64 + rc1];
                #pragma unroll
                for (int qf = 0; qf < 4; ++qf) {
                    f32x4 zc = fzero;
                    zc = __builtin_amdgcn_mfma_f32_16x16x32_bf16(ka0, qb[qf][0], zc, 0, 0, 0);
                    s[qf][n2] = __builtin_amdgcn_mfma_f32_16x16x32_bf16(ka1, qb[qf][1], zc, 0, 0, 0);
                }
            }
            __builtin_amdgcn_s_setprio(0);

            bf16x8 pa[4];
            #pragma unroll
            for (int qf = 0; qf < 4; ++qf) {
                #pragma unroll
                for (int n2 = 0; n2 < 2; ++n2)
                    #pragma unroll
                    for (int r = 0; r < 4; ++r) s[qf][n2][r] = fast_exp2(s[qf][n2][r]);
                unsigned pw[4];
                #pragma unroll
                for (int p = 0; p < 2; ++p) {
                    unsigned X, Y;
                    asm("v_cvt_pk_bf16_f32 %0, %1, %2"
                        : "=v"(X) : "v"(s[qf][0][2 * p]), "v"(s[qf][0][2 * p + 1]));
                    asm("v_cvt_pk_bf16_f32 %0, %1, %2"
                        : "=v"(Y) : "v"(s[qf][1][2 * p]), "v"(s[qf][1][2 * p + 1]));
                    asm volatile("v_permlane32_swap_b32 %0, %1" : "+v"(X), "+v"(Y));
                    asm volatile("v_permlane16_swap_b32 %0, %1" : "+v"(X), "+v"(Y));
                    pw[p] = X;
                    pw[p + 2] = Y;
                }
                #pragma unroll
                for (int j = 0; j < 4; ++j) ((unsigned*)&pa[qf])[j] = pw[j];
            }

            __builtin_amdgcn_s_setprio(1);
            #pragma unroll
            for (int c = 0; c < 4; ++c) {
                const int slot = ((wk * 8 + st * 4 + hi) ^ lo) * 8;
                bf16x8 vbf = *(const bf16x8*)&Vc[(c * 16 + lo) * 128 + slot];
                #pragma unroll
                for (int qf = 0; qf < 4; ++qf)
                    O[qf][c] = __builtin_amdgcn_mfma_f32_16x16x32_bf16(pa[qf], vbf, O[qf][c], 0, 0, 0);
            }
            #pragma unroll
            for (int qf = 0; qf < 4; ++qf)
                lacc[qf] = __builtin_amdgcn_mfma_f32_16x16x32_bf16(pa[qf], ones, lacc[qf], 0, 0, 0);
            __builtin_amdgcn_s_setprio(0);
        }
    }

    __syncthreads();
    float* Obuf = (float*)SM2;                 // [64 d][132] f32
    float* Lbuf = (float*)(SM2 + 16896);       // 128 f32

    if (wk == 1) {
        #pragma unroll
        for (int qf = 0; qf < 4; ++qf) {
            #pragma unroll
            for (int c = 0; c < 4; ++c)
                *(float4*)&Obuf[(c * 16 + lo) * 132 + wq * 64 + qf * 16 + hi * 4] =
                    *(float4*)&O[qf][c];
            #pragma unroll
            for (int r = 0; r < 4; ++r)
                Lbuf[wq * 64 + qf * 16 + hi * 4 + r] = lacc[qf][r];
        }
    }
    __syncthreads();
    if (wk == 0) {
        #pragma unroll
        for (int qf = 0; qf < 4; ++qf) {
            float linv[4];
            #pragma unroll
            for (int r = 0; r < 4; ++r)
                linv[r] = 1.0f / (lacc[qf][r] + Lbuf[wq * 64 + qf * 16 + hi * 4 + r]);
            #pragma unroll
            for (int c = 0; c < 4; ++c) {
                float4 p = *(float4*)&Obuf[(c * 16 + lo) * 132 + wq * 64 + qf * 16 + hi * 4];
                #pragma unroll
                for (int r = 0; r < 4; ++r) {
                    int q = q0 + wq * 64 + qf * 16 + hi * 4 + r;
                    out[(size_t)b * S_ * HID_ + (size_t)q * HID_ + h * HD_ + c * 16 + lo] =
                        (O[qf][c][r] + (&p.x)[r]) * linv[r];
                }
            }
        }
    }
}

extern "C" void kernel_launch(void* const* d_in, const int* in_sizes, int n_in,
                              void* d_out, int out_size, void* d_ws, size_t ws_size,
                              hipStream_t stream) {
    const float* hs1 = (const float*)d_in[0];
    const float* hs2 = (const float*)d_in[1];
    const float* Wq  = (const float*)d_in[2];
    const float* bq  = (const float*)d_in[3];
    const float* Wk  = (const float*)d_in[4];
    const float* bk  = (const float*)d_in[5];
    const float* Wv  = (const float*)d_in[6];
    const float* bv  = (const float*)d_in[7];
    float* out = (float*)d_out;

    const size_t XY = (size_t)B_ * S_ * HID_;   // 4194304
    const size_t WW = (size_t)HID_ * HID_;      // 1048576
    unsigned short* Qb  = (unsigned short*)d_ws;
    unsigned short* Kb  = Qb + XY;
    unsigned short* Vb  = Kb + XY;              // V transposed [b][h*64+d][s]
    unsigned short* X1b = Vb + XY;
    unsigned short* X2b = X1b + XY;
    unsigned short* Wqb = X2b + XY;
    unsigned short* Wkb = Wqb + WW;
    unsigned short* Wvb = Wkb + WW;

    cvt_all<<<5632, 256, 0, stream>>>(hs1, hs2, Wq, Wk, Wv, X1b, X2b, Wqb, Wkb, Wvb);
    qkv_gemm<<<dim3(32, 8, 3), 256, 0, stream>>>(X1b, X2b, Wqb, Wkb, Wvb,
                                                 bq, bk, bv, Qb, Kb, Vb);
    attn_fwd<<<dim3(16, 32), 256, 0, stream>>>(Qb, Kb, Vb, out);
}